// Round 14
// baseline (207.756 us; speedup 1.0000x reference)
//
#include <hip/hip_runtime.h>
#include <math.h>

#define DM 256
#define LSEQ 2048
#define BATCH 8
#define NLAYER 8
#define EMAX 192
#define LN_EPS 1e-5f
#define BM 16
#define BLKS 128                    // blocks per batch
#define NPROD 13                    // producer blocks (rows t<=192: blk 0..12)
#define TAILB 115                   // first tail block (rows u<=192: blk 115..127)

// LDS: Ah [16 rows][512 B, XOR-swizzled] @0 ; Al @8192 ; red [16][10] f32 @16384
#define AL_OFF  8192
#define RED_OFF 16384
#define SMEM_SZ (RED_OFF + 640)     // 17024 B -> grid-limited 4 blocks/CU

typedef float f32x4 __attribute__((ext_vector_type(4)));
typedef short bf16x8 __attribute__((ext_vector_type(8)));
typedef unsigned short u16;
typedef unsigned short u16x4 __attribute__((ext_vector_type(4)));
typedef unsigned short u16x8 __attribute__((ext_vector_type(8)));

union V8 { u16x8 u; bf16x8 b; };

// branch-free erf, Abramowitz-Stegun 7.1.26, |err| <= 1.5e-7
__device__ __forceinline__ float erf_fast(float x) {
    float ax = fabsf(x);
    float t = __builtin_amdgcn_rcpf(fmaf(0.3275911f, ax, 1.f));
    float p = fmaf(t, 1.061405429f, -1.453152027f);
    p = fmaf(t, p, 1.421413741f);
    p = fmaf(t, p, -0.284496736f);
    p = fmaf(t, p, 0.254829592f);
    p = p * t;
    float e = __expf(-ax * ax);
    float r = 1.f - p * e;
    return copysignf(r, x);
}

__device__ __forceinline__ float gelu_fast(float v) {
    return 0.5f * v * (1.f + erf_fast(v * 0.70710678118654752f));
}

// split fp32 -> bf16 hi (truncated, exact-subtractable) + bf16 lo (RNE of remainder)
__device__ __forceinline__ void split2(float g, u16& hi, u16& lo) {
    unsigned u = __float_as_uint(g);
    hi = (u16)(u >> 16);
    float fh = __uint_as_float(u & 0xFFFF0000u);
    float r = g - fh;
    unsigned v = __float_as_uint(r);
    v = v + 0x7FFFu + ((v >> 16) & 1u);
    lo = (u16)(v >> 16);
}

// A-tile write address for (row, k0=wn*64+fr*4): unit = wn*8+(fr>>1), 8B half = fr&1
__device__ __forceinline__ int a_addr(int row, int wn, int fr) {
    int unit = wn * 8 + (fr >> 1);
    return row * 512 + ((unit ^ (row & 7)) << 4) + (fr & 1) * 8;
}

// ---------------- merged prep: blocks 0..255 = pW split+pack; 256..263 = prep0 ----------------
// COLUMN-PERMUTED packing: packed[((cg*8+ks)*64+lane)*8+j] = pW[col][k] with
// col = (cg>>2)*64 + fr*4 + (cg&3)   (tile n's lane fr supplies actual col wn*64+fr*4+n)
// k = ks*32 + fq*8 + j
__global__ void k_prep(const float* __restrict__ pW, u16* __restrict__ pWh,
                       u16* __restrict__ pWl,
                       const float* __restrict__ x, const float* __restrict__ inW,
                       const float* __restrict__ inb, const float* __restrict__ Ap,
                       const float* __restrict__ Bp, const float* __restrict__ Cp,
                       float* __restrict__ P_all, float* __restrict__ logA_all,
                       float* __restrict__ CB_all, float* __restrict__ pooled,
                       int* __restrict__ flags) {
    if (blockIdx.x < 256) {
        int i = blockIdx.x * 256 + threadIdx.x;
        int e = i * 8;
        int l = e >> 16;
        int r = e & 65535;
        int cg = r >> 12;
        int ks = (r >> 9) & 7;
        int lane = (r >> 3) & 63;
        int fq = lane >> 4, fr = lane & 15;
        int col = (cg >> 2) * 64 + fr * 4 + (cg & 3);   // permuted
        int k = ks * 32 + fq * 8;
        const float* src = pW + l * 65536 + col * 256 + k;
        float4 w0 = *(const float4*)src;
        float4 w1 = *(const float4*)(src + 4);
        float vv[8] = {w0.x, w0.y, w0.z, w0.w, w1.x, w1.y, w1.z, w1.w};
        u16 sh[8], sl[8];
#pragma unroll
        for (int j = 0; j < 8; ++j) split2(vv[j], sh[j], sl[j]);
        u16x8 vh = {sh[0], sh[1], sh[2], sh[3], sh[4], sh[5], sh[6], sh[7]};
        u16x8 vl = {sl[0], sl[1], sl[2], sl[3], sl[4], sl[5], sl[6], sl[7]};
        *(u16x8*)&pWh[e] = vh;
        *(u16x8*)&pWl[e] = vl;
    } else {
        int b = blockIdx.x - 256;
        int c = threadIdx.x;
        float A0 = 1.f / (1.f + expf(-Ap[c]));
        float iw = inW[c], ib = inb[c];
        const float* xb = x + b * LSEQ;
        float pw = 1.f, acc = 0.f;
        for (int t = 0; t <= EMAX; ++t) {
            acc += (xb[t] * iw + ib) * pw;
            pw *= A0;
        }
        P_all[b * DM + c] = acc;
        for (int l = 1; l < NLAYER; ++l) P_all[l * BATCH * DM + b * DM + c] = 0.f;
        for (int e = 0; e < 4; ++e) pooled[e * BATCH * DM + b * DM + c] = 0.f;
        if (b == 0) {
            for (int l = 0; l < NLAYER; ++l) {
                float Al = 1.f / (1.f + expf(-Ap[l * DM + c]));
                logA_all[l * DM + c] = logf(Al);
                CB_all[l * DM + c]   = Bp[l * DM + c] * Cp[l * DM + c];
            }
            if (c < NLAYER * BATCH) flags[c] = 0;
        }
    }
}

// ---------------- persistent-tile fused kernel: 16 rows through all 8 layers ----------------
// 1024 blocks (4/CU), 256 thr = 4 waves (wave wn = 64-col slice). No hT, no stage phase:
// epilogue writes next layer's A fragments directly (contiguous 4-col per thread).
__global__ __launch_bounds__(256, 4) void k_fused(
    const float* __restrict__ x, const float* __restrict__ inW,
    const float* __restrict__ inb,
    const u16* __restrict__ pWh, const u16* __restrict__ pWl,
    const float* __restrict__ Dp_all, const float* __restrict__ pb_all,
    const float* __restrict__ lng_all, const float* __restrict__ lnb_all,
    const float* __restrict__ logA_all, const float* __restrict__ CB_all,
    float* __restrict__ P_all, float* __restrict__ pooled,
    int* __restrict__ flags)
{
    __shared__ __align__(16) char smem[SMEM_SZ];

    int tid  = threadIdx.x;
    int lane = tid & 63;
    int wn   = tid >> 6;            // 0..3 col slice (64 cols)
    int fr   = lane & 15;
    int fq   = lane >> 4;

    int b    = blockIdx.x >> 7;
    int blk  = blockIdx.x & 127;
    int brow = b * LSEQ + blk * BM;
    bool isTail = (blk >= TAILB);
    bool isProd = (blk < NPROD);

    int col0 = wn * 64 + fr * 4;    // 4 contiguous cols col0..col0+3
    float hreg[4][4];               // [n][r] : h/o for (row=fq*4+r, col=col0+n)

    // ---- l=0 init: h from x in registers; write A(0) fragments (with tail term) ----
    {
        float4 wi = *(const float4*)&inW[col0];
        float4 bi = *(const float4*)&inb[col0];
        float4 d0 = *(const float4*)&Dp_all[col0];
        float4 la0, cb0, P0;
        if (isTail) {
            la0 = *(const float4*)&logA_all[col0];
            cb0 = *(const float4*)&CB_all[col0];
            P0  = *(const float4*)&P_all[b * DM + col0];
        }
#pragma unroll
        for (int r = 0; r < 4; ++r) {
            int row = fq * 4 + r;
            int gr  = brow + row;
            float xv = x[gr];
            int u = (LSEQ - 1) - (gr & (LSEQ - 1));
            bool tl = isTail && (u <= EMAX);
            float uf = (float)u;
            float v[4];
            v[0] = fmaf(xv, wi.x, bi.x); hreg[0][r] = v[0];
            v[1] = fmaf(xv, wi.y, bi.y); hreg[1][r] = v[1];
            v[2] = fmaf(xv, wi.z, bi.z); hreg[2][r] = v[2];
            v[3] = fmaf(xv, wi.w, bi.w); hreg[3][r] = v[3];
            v[0] *= d0.x; v[1] *= d0.y; v[2] *= d0.z; v[3] *= d0.w;
            if (tl) {
                v[0] += cb0.x * __expf(uf * la0.x) * P0.x;
                v[1] += cb0.y * __expf(uf * la0.y) * P0.y;
                v[2] += cb0.z * __expf(uf * la0.z) * P0.z;
                v[3] += cb0.w * __expf(uf * la0.w) * P0.w;
            }
            u16 sh[4], sl[4];
#pragma unroll
            for (int n = 0; n < 4; ++n) split2(gelu_fast(v[n]), sh[n], sl[n]);
            u16x4 vh = {sh[0], sh[1], sh[2], sh[3]};
            u16x4 vl = {sl[0], sl[1], sl[2], sl[3]};
            int aby = a_addr(row, wn, fr);
            *(u16x4*)(smem + aby) = vh;
            *(u16x4*)(smem + AL_OFF + aby) = vl;
        }
    }

    // B fragment ring (depth-1, 2 slots)
    V8 bhd[2][4], bld[2][4];
    {
        const u16* bhp0 = pWh + wn * 16384 + lane * 8;
        const u16* blp0 = pWl + wn * 16384 + lane * 8;
#pragma unroll
        for (int n = 0; n < 4; ++n) {
            bhd[0][n].u = *(const u16x8*)&bhp0[n * 4096];
            bld[0][n].u = *(const u16x8*)&blp0[n * 4096];
        }
    }
    __syncthreads();   // A(0) ready

    for (int l = 0; l < NLAYER; ++l) {
        const u16* bhp = pWh + (size_t)l * 65536 + wn * 16384 + lane * 8;
        const u16* blp = pWl + (size_t)l * 65536 + wn * 16384 + lane * 8;

        // ---- MFMA: A from LDS (row = fr), B ring depth-1 ----
        f32x4 acc[4];
#pragma unroll
        for (int n = 0; n < 4; ++n) acc[n] = (f32x4){0.f, 0.f, 0.f, 0.f};

#pragma unroll
        for (int ks = 0; ks < 8; ++ks) {
            int cur = ks & 1, nxt = cur ^ 1;
            if (ks < 7) {
#pragma unroll
                for (int n = 0; n < 4; ++n) {
                    bhd[nxt][n].u = *(const u16x8*)&bhp[n * 4096 + (ks + 1) * 512];
                    bld[nxt][n].u = *(const u16x8*)&blp[n * 4096 + (ks + 1) * 512];
                }
            }
            V8 ah, al;
            {
                int aby = fr * 512 + (((ks * 4 + fq) ^ (fr & 7)) << 4);
                ah.u = *(const u16x8*)(smem + aby);
                al.u = *(const u16x8*)(smem + AL_OFF + aby);
            }
#pragma unroll
            for (int n = 0; n < 4; ++n) {
                acc[n] = __builtin_amdgcn_mfma_f32_16x16x32_bf16(ah.b, bhd[cur][n].b, acc[n], 0, 0, 0);
                acc[n] = __builtin_amdgcn_mfma_f32_16x16x32_bf16(ah.b, bld[cur][n].b, acc[n], 0, 0, 0);
                acc[n] = __builtin_amdgcn_mfma_f32_16x16x32_bf16(al.b, bhd[cur][n].b, acc[n], 0, 0, 0);
            }
        }

        // ---- p1: y = h + out2 + pb; row sums; cross-wave reduce ----
        float4 pbv = *(const float4*)&pb_all[l * DM + col0];
        float4 lgv = *(const float4*)&lng_all[l * DM + col0];
        float4 lbv = *(const float4*)&lnb_all[l * DM + col0];
        float s[4], ss[4];
#pragma unroll
        for (int r = 0; r < 4; ++r) {
            float y0 = hreg[0][r] + acc[0][r] + pbv.x;
            float y1 = hreg[1][r] + acc[1][r] + pbv.y;
            float y2 = hreg[2][r] + acc[2][r] + pbv.z;
            float y3 = hreg[3][r] + acc[3][r] + pbv.w;
            acc[0][r] = y0; acc[1][r] = y1; acc[2][r] = y2; acc[3][r] = y3;
            s[r]  = y0 + y1 + y2 + y3;
            ss[r] = y0 * y0 + y1 * y1 + y2 * y2 + y3 * y3;
        }
#pragma unroll
        for (int r = 0; r < 4; ++r)
#pragma unroll
            for (int msk = 1; msk < 16; msk <<= 1) {
                s[r]  += __shfl_xor(s[r],  msk);
                ss[r] += __shfl_xor(ss[r], msk);
            }
        if (fr == 0) {
#pragma unroll
            for (int r = 0; r < 4; ++r) {
                int row = fq * 4 + r;
                *(float*)(smem + RED_OFF + (row * 10 + wn * 2)     * 4) = s[r];
                *(float*)(smem + RED_OFF + (row * 10 + wn * 2 + 1) * 4) = ss[r];
            }
        }
        __syncthreads();   // bar B: red ready; all A(l) reads done

        // ---- p2: LN -> o; hreg=o; write A(l+1) fragments; pooled; P_next ----
        float mean[4], rstd[4];
#pragma unroll
        for (int r = 0; r < 4; ++r) {
            int row = fq * 4 + r;
            float st = 0.f, sst = 0.f;
#pragma unroll
            for (int w = 0; w < 4; ++w) {
                st  += *(const float*)(smem + RED_OFF + (row * 10 + w * 2)     * 4);
                sst += *(const float*)(smem + RED_OFF + (row * 10 + w * 2 + 1) * 4);
            }
            float mu = st * (1.f / 256.f);
            float var = sst * (1.f / 256.f) - mu * mu;
            mean[r] = mu;
            rstd[r] = rsqrtf(var + LN_EPS);
        }
        int slot = (l == 1) ? 0 : (l == 3) ? 1 : (l == 5) ? 2 : (l == 7) ? 3 : -1;
        bool last = (l == NLAYER - 1);
        bool prod = !last && isProd;
        float4 Dnv, lanv;
        if (!last) Dnv = *(const float4*)&Dp_all[(l + 1) * DM + col0];
        if (prod)  lanv = *(const float4*)&logA_all[(l + 1) * DM + col0];
        float cs[4] = {0.f, 0.f, 0.f, 0.f};
        float pc[4] = {0.f, 0.f, 0.f, 0.f};
#pragma unroll
        for (int r = 0; r < 4; ++r) {
            int row  = fq * 4 + r;
            int trow = blk * BM + row;
            float o0 = (acc[0][r] - mean[r]) * rstd[r] * lgv.x + lbv.x;
            float o1 = (acc[1][r] - mean[r]) * rstd[r] * lgv.y + lbv.y;
            float o2 = (acc[2][r] - mean[r]) * rstd[r] * lgv.z + lbv.z;
            float o3 = (acc[3][r] - mean[r]) * rstd[r] * lgv.w + lbv.w;
            hreg[0][r] = o0; hreg[1][r] = o1; hreg[2][r] = o2; hreg[3][r] = o3;
            if (slot >= 0) { cs[0] += o0; cs[1] += o1; cs[2] += o2; cs[3] += o3; }
            if (prod && trow <= EMAX) {
                float tf = (float)trow;
                pc[0] += o0 * __expf(tf * lanv.x);
                pc[1] += o1 * __expf(tf * lanv.y);
                pc[2] += o2 * __expf(tf * lanv.z);
                pc[3] += o3 * __expf(tf * lanv.w);
            }
            if (!last) {
                u16 sh[4], sl[4];
                split2(gelu_fast(Dnv.x * o0), sh[0], sl[0]);
                split2(gelu_fast(Dnv.y * o1), sh[1], sl[1]);
                split2(gelu_fast(Dnv.z * o2), sh[2], sl[2]);
                split2(gelu_fast(Dnv.w * o3), sh[3], sl[3]);
                u16x4 vh = {sh[0], sh[1], sh[2], sh[3]};
                u16x4 vl = {sl[0], sl[1], sl[2], sl[3]};
                int aby = a_addr(row, wn, fr);
                *(u16x4*)(smem + aby) = vh;
                *(u16x4*)(smem + AL_OFF + aby) = vl;
            }
        }
        if (slot >= 0) {
#pragma unroll
            for (int n = 0; n < 4; ++n) {
                cs[n] += __shfl_xor(cs[n], 16);
                cs[n] += __shfl_xor(cs[n], 32);
            }
            if (lane < 16) {
#pragma unroll
                for (int n = 0; n < 4; ++n)
                    atomicAdd(&pooled[slot * (BATCH * DM) + b * DM + wn * 64 + lane * 4 + n], cs[n]);
            }
        }
        if (prod) {
#pragma unroll
            for (int n = 0; n < 4; ++n) {
                pc[n] += __shfl_xor(pc[n], 16);
                pc[n] += __shfl_xor(pc[n], 32);
            }
            if (lane < 16) {
#pragma unroll
                for (int n = 0; n < 4; ++n)
                    atomicAdd(&P_all[(size_t)(l + 1) * BATCH * DM + b * DM + wn * 64 + lane * 4 + n], pc[n]);
            }
        }

        if (!last) {
            // preload next layer's B slot 0
            const u16* bhpN = pWh + (size_t)(l + 1) * 65536 + wn * 16384 + lane * 8;
            const u16* blpN = pWl + (size_t)(l + 1) * 65536 + wn * 16384 + lane * 8;
#pragma unroll
            for (int n = 0; n < 4; ++n) {
                bhd[0][n].u = *(const u16x8*)&bhpN[n * 4096];
                bld[0][n].u = *(const u16x8*)&blpN[n * 4096];
            }
        }
        __syncthreads();   // bar C: A(l+1) staged; P atomics drained

        if (!last) {
            if (prod && tid == 0)
                __hip_atomic_fetch_add(&flags[(l + 1) * BATCH + b], 1,
                                       __ATOMIC_RELEASE, __HIP_MEMORY_SCOPE_AGENT);
            if (isTail) {
                // wait for P[l+1]; fix tail rows' A fragments in place
                if (tid == 0) {
                    while (__hip_atomic_load(&flags[(l + 1) * BATCH + b], __ATOMIC_ACQUIRE,
                                             __HIP_MEMORY_SCOPE_AGENT) < NPROD)
                        __builtin_amdgcn_s_sleep(2);
                }
                __syncthreads();
                float4 lanx = *(const float4*)&logA_all[(l + 1) * DM + col0];
                float4 cbnx = *(const float4*)&CB_all[(l + 1) * DM + col0];
                float Pn[4];
#pragma unroll
                for (int n = 0; n < 4; ++n)
                    Pn[n] = __hip_atomic_load(
                        &P_all[(size_t)(l + 1) * BATCH * DM + b * DM + col0 + n],
                        __ATOMIC_RELAXED, __HIP_MEMORY_SCOPE_AGENT);
                float lan[4] = {lanx.x, lanx.y, lanx.z, lanx.w};
                float cbn[4] = {cbnx.x, cbnx.y, cbnx.z, cbnx.w};
                float Dn[4]  = {Dnv.x, Dnv.y, Dnv.z, Dnv.w};
#pragma unroll
                for (int r = 0; r < 4; ++r) {
                    int row = fq * 4 + r;
                    int u = (LSEQ - 1) - ((brow + row) & (LSEQ - 1));
                    if (u <= EMAX) {
                        float uf = (float)u;
                        u16 sh[4], sl[4];
#pragma unroll
                        for (int n = 0; n < 4; ++n) {
                            float v = Dn[n] * hreg[n][r] + cbn[n] * __expf(uf * lan[n]) * Pn[n];
                            split2(gelu_fast(v), sh[n], sl[n]);
                        }
                        u16x4 vh = {sh[0], sh[1], sh[2], sh[3]};
                        u16x4 vl = {sl[0], sl[1], sl[2], sl[3]};
                        int aby = a_addr(row, wn, fr);
                        *(u16x4*)(smem + aby) = vh;
                        *(u16x4*)(smem + AL_OFF + aby) = vl;
                    }
                }
                __syncthreads();
            }
        }
    }
}

// ---------------- head ----------------
__global__ void k_head(const float* __restrict__ pooled, const float* __restrict__ hW,
                       const float* __restrict__ hb, float* __restrict__ out) {
    int tid = threadIdx.x;
    if (tid >= 96) return;
    int e = tid / 24;
    int r = tid % 24;
    int b = r / 3;
    int n = r % 3;
    const float* pv = &pooled[e * (BATCH * DM) + b * DM];
    const float* wv = &hW[(e * 3 + n) * DM];
    float acc = 0.f;
    for (int c = 0; c < DM; ++c) acc += pv[c] * wv[c];
    out[e * 24 + b * 3 + n] = acc * (1.f / (float)LSEQ) + hb[e * 3 + n];
}

extern "C" void kernel_launch(void* const* d_in, const int* in_sizes, int n_in,
                              void* d_out, int out_size, void* d_ws, size_t ws_size,
                              hipStream_t stream) {
    const float* x   = (const float*)d_in[0];
    const float* inW = (const float*)d_in[1];
    const float* inb = (const float*)d_in[2];
    const float* Ap  = (const float*)d_in[3];
    const float* Bp  = (const float*)d_in[4];
    const float* Cp  = (const float*)d_in[5];
    const float* Dp  = (const float*)d_in[6];
    const float* pW  = (const float*)d_in[7];
    const float* pb  = (const float*)d_in[8];
    const float* lng = (const float*)d_in[9];
    const float* lnb = (const float*)d_in[10];
    const float* hW  = (const float*)d_in[11];
    const float* hb  = (const float*)d_in[12];
    float* out = (float*)d_out;

    float* ws = (float*)d_ws;
    float* P_all    = ws;                            // 16384
    float* logA_all = P_all + NLAYER * BATCH * DM;   // 2048
    float* CB_all   = logA_all + NLAYER * DM;        // 2048
    float* pooled   = CB_all + NLAYER * DM;          // 8192
    u16* pWh        = (u16*)(pooled + 4 * BATCH * DM);   // 524288 u16
    u16* pWl        = pWh + NLAYER * DM * DM;            // 524288 u16
    int* flags      = (int*)(pWl + NLAYER * DM * DM);    // 64 ints

    k_prep<<<264, 256, 0, stream>>>(pW, pWh, pWl, x, inW, inb, Ap, Bp, Cp,
                                    P_all, logA_all, CB_all, pooled, flags);
    k_fused<<<BATCH * BLKS, 256, 0, stream>>>(
        x, inW, inb, pWh, pWl, Dp, pb, lng, lnb,
        logA_all, CB_all, P_all, pooled, flags);
    k_head<<<1, 128, 0, stream>>>(pooled, hW, hb, out);
}

// Round 15
// 126.780 us; speedup vs baseline: 1.6387x; 1.6387x over previous
//
#include <hip/hip_runtime.h>
#include <math.h>

#define DM 256
#define LSEQ 2048
#define BATCH 8
#define NLAYER 8
#define EMAX 192
#define LN_EPS 1e-5f
#define BM 32
#define BLKS 64                     // blocks per batch
#define NPROD 7                     // producer blocks (rows t<=192: blk 0..6)
#define TAILB 57                    // first tail block (rows u<=192: blk 57..63)

// LDS: Ah [32 rows][512 B, XOR-swizzled] @0 ; Al @16384 ; red [32][10] f32 @32768
#define AL_OFF  16384
#define RED_OFF 32768
#define SMEM_SZ (RED_OFF + 1280)    // 34048 B -> 3-4 blocks/CU (VGPR-limited ~3)

typedef float f32x4 __attribute__((ext_vector_type(4)));
typedef short bf16x8 __attribute__((ext_vector_type(8)));
typedef unsigned short u16;
typedef unsigned short u16x4 __attribute__((ext_vector_type(4)));
typedef unsigned short u16x8 __attribute__((ext_vector_type(8)));

union V8 { u16x8 u; bf16x8 b; };

// branch-free erf, Abramowitz-Stegun 7.1.26, |err| <= 1.5e-7
__device__ __forceinline__ float erf_fast(float x) {
    float ax = fabsf(x);
    float t = __builtin_amdgcn_rcpf(fmaf(0.3275911f, ax, 1.f));
    float p = fmaf(t, 1.061405429f, -1.453152027f);
    p = fmaf(t, p, 1.421413741f);
    p = fmaf(t, p, -0.284496736f);
    p = fmaf(t, p, 0.254829592f);
    p = p * t;
    float e = __expf(-ax * ax);
    float r = 1.f - p * e;
    return copysignf(r, x);
}

__device__ __forceinline__ float gelu_fast(float v) {
    return 0.5f * v * (1.f + erf_fast(v * 0.70710678118654752f));
}

// split fp32 -> bf16 hi (truncated, exact-subtractable) + bf16 lo (RNE of remainder)
__device__ __forceinline__ void split2(float g, u16& hi, u16& lo) {
    unsigned u = __float_as_uint(g);
    hi = (u16)(u >> 16);
    float fh = __uint_as_float(u & 0xFFFF0000u);
    float r = g - fh;
    unsigned v = __float_as_uint(r);
    v = v + 0x7FFFu + ((v >> 16) & 1u);
    lo = (u16)(v >> 16);
}

// A-tile write address for (row, k0=wn*64+fr*4): unit = wn*8+(fr>>1), 8B half = fr&1
// (verified r14: matches the MFMA read mapping)
__device__ __forceinline__ int a_addr(int row, int wn, int fr) {
    int unit = wn * 8 + (fr >> 1);
    return row * 512 + ((unit ^ (row & 7)) << 4) + (fr & 1) * 8;
}

// ---------------- merged prep: blocks 0..255 = pW split+pack; 256..263 = prep0 ----------------
// COLUMN-PERMUTED packing (verified r14): packed[((cg*8+ks)*64+lane)*8+j] = pW[col][k],
// col = (cg>>2)*64 + fr*4 + (cg&3), k = ks*32 + fq*8 + j
__global__ void k_prep(const float* __restrict__ pW, u16* __restrict__ pWh,
                       u16* __restrict__ pWl,
                       const float* __restrict__ x, const float* __restrict__ inW,
                       const float* __restrict__ inb, const float* __restrict__ Ap,
                       const float* __restrict__ Bp, const float* __restrict__ Cp,
                       float* __restrict__ P_all, float* __restrict__ logA_all,
                       float* __restrict__ CB_all, float* __restrict__ pooled,
                       int* __restrict__ flags) {
    if (blockIdx.x < 256) {
        int i = blockIdx.x * 256 + threadIdx.x;
        int e = i * 8;
        int l = e >> 16;
        int r = e & 65535;
        int cg = r >> 12;
        int ks = (r >> 9) & 7;
        int lane = (r >> 3) & 63;
        int fq = lane >> 4, fr = lane & 15;
        int col = (cg >> 2) * 64 + fr * 4 + (cg & 3);   // permuted
        int k = ks * 32 + fq * 8;
        const float* src = pW + l * 65536 + col * 256 + k;
        float4 w0 = *(const float4*)src;
        float4 w1 = *(const float4*)(src + 4);
        float vv[8] = {w0.x, w0.y, w0.z, w0.w, w1.x, w1.y, w1.z, w1.w};
        u16 sh[8], sl[8];
#pragma unroll
        for (int j = 0; j < 8; ++j) split2(vv[j], sh[j], sl[j]);
        u16x8 vh = {sh[0], sh[1], sh[2], sh[3], sh[4], sh[5], sh[6], sh[7]};
        u16x8 vl = {sl[0], sl[1], sl[2], sl[3], sl[4], sl[5], sl[6], sl[7]};
        *(u16x8*)&pWh[e] = vh;
        *(u16x8*)&pWl[e] = vl;
    } else {
        int b = blockIdx.x - 256;
        int c = threadIdx.x;
        float A0 = 1.f / (1.f + expf(-Ap[c]));
        float iw = inW[c], ib = inb[c];
        const float* xb = x + b * LSEQ;
        float pw = 1.f, acc = 0.f;
        for (int t = 0; t <= EMAX; ++t) {
            acc += (xb[t] * iw + ib) * pw;
            pw *= A0;
        }
        P_all[b * DM + c] = acc;
        for (int l = 1; l < NLAYER; ++l) P_all[l * BATCH * DM + b * DM + c] = 0.f;
        for (int e = 0; e < 4; ++e) pooled[e * BATCH * DM + b * DM + c] = 0.f;
        if (b == 0) {
            for (int l = 0; l < NLAYER; ++l) {
                float Al = 1.f / (1.f + expf(-Ap[l * DM + c]));
                logA_all[l * DM + c] = logf(Al);
                CB_all[l * DM + c]   = Bp[l * DM + c] * Cp[l * DM + c];
            }
            if (c < NLAYER * BATCH) flags[c] = 0;
        }
    }
}

// ---------------- persistent-tile fused kernel: 32 rows through all 8 layers ----------------
// 512 blocks, 256 thr = 4 waves (wave wn = 64-col slice; m = 2 row halves). No hT, no
// stage phase: the epilogue writes next layer's A fragments directly (4 contiguous cols
// per thread via the permuted B packing). 2 barriers/layer.
__global__ __launch_bounds__(256, 1) void k_fused(
    const float* __restrict__ x, const float* __restrict__ inW,
    const float* __restrict__ inb,
    const u16* __restrict__ pWh, const u16* __restrict__ pWl,
    const float* __restrict__ Dp_all, const float* __restrict__ pb_all,
    const float* __restrict__ lng_all, const float* __restrict__ lnb_all,
    const float* __restrict__ logA_all, const float* __restrict__ CB_all,
    float* __restrict__ P_all, float* __restrict__ pooled,
    int* __restrict__ flags)
{
    __shared__ __align__(16) char smem[SMEM_SZ];

    int tid  = threadIdx.x;
    int lane = tid & 63;
    int wn   = tid >> 6;            // 0..3 col slice (64 cols)
    int fr   = lane & 15;
    int fq   = lane >> 4;

    int b    = blockIdx.x >> 6;
    int blk  = blockIdx.x & 63;
    int brow = b * LSEQ + blk * BM;
    bool isTail = (blk >= TAILB);
    bool isProd = (blk < NPROD);

    int col0 = wn * 64 + fr * 4;    // 4 contiguous cols per thread
    float hreg[2][4][4];            // [m][n][r]: h/o at (row=m*16+fq*4+r, col=col0+n)

    // ---- l=0 init: h from x in registers; write A(0) fragments (with tail term) ----
    {
        float4 wi = *(const float4*)&inW[col0];
        float4 bi = *(const float4*)&inb[col0];
        float4 d0 = *(const float4*)&Dp_all[col0];
        float4 la0, cb0, P0;
        if (isTail) {
            la0 = *(const float4*)&logA_all[col0];
            cb0 = *(const float4*)&CB_all[col0];
            P0  = *(const float4*)&P_all[b * DM + col0];
        }
#pragma unroll
        for (int m = 0; m < 2; ++m)
#pragma unroll
            for (int r = 0; r < 4; ++r) {
                int row = m * 16 + fq * 4 + r;
                int gr  = brow + row;
                float xv = x[gr];
                int u = (LSEQ - 1) - (gr & (LSEQ - 1));
                bool tl = isTail && (u <= EMAX);
                float uf = (float)u;
                float v[4];
                v[0] = fmaf(xv, wi.x, bi.x); hreg[m][0][r] = v[0];
                v[1] = fmaf(xv, wi.y, bi.y); hreg[m][1][r] = v[1];
                v[2] = fmaf(xv, wi.z, bi.z); hreg[m][2][r] = v[2];
                v[3] = fmaf(xv, wi.w, bi.w); hreg[m][3][r] = v[3];
                v[0] *= d0.x; v[1] *= d0.y; v[2] *= d0.z; v[3] *= d0.w;
                if (tl) {
                    v[0] += cb0.x * __expf(uf * la0.x) * P0.x;
                    v[1] += cb0.y * __expf(uf * la0.y) * P0.y;
                    v[2] += cb0.z * __expf(uf * la0.z) * P0.z;
                    v[3] += cb0.w * __expf(uf * la0.w) * P0.w;
                }
                u16 sh[4], sl[4];
#pragma unroll
                for (int n = 0; n < 4; ++n) split2(gelu_fast(v[n]), sh[n], sl[n]);
                u16x4 vh = {sh[0], sh[1], sh[2], sh[3]};
                u16x4 vl = {sl[0], sl[1], sl[2], sl[3]};
                int aby = a_addr(row, wn, fr);
                *(u16x4*)(smem + aby) = vh;
                *(u16x4*)(smem + AL_OFF + aby) = vl;
            }
    }

    // B fragment ring (depth-1, 2 slots)
    V8 bhd[2][4], bld[2][4];
    {
        const u16* bhp0 = pWh + wn * 16384 + lane * 8;
        const u16* blp0 = pWl + wn * 16384 + lane * 8;
#pragma unroll
        for (int n = 0; n < 4; ++n) {
            bhd[0][n].u = *(const u16x8*)&bhp0[n * 4096];
            bld[0][n].u = *(const u16x8*)&blp0[n * 4096];
        }
    }
    __syncthreads();   // A(0) ready

    for (int l = 0; l < NLAYER; ++l) {
        const u16* bhp = pWh + (size_t)l * 65536 + wn * 16384 + lane * 8;
        const u16* blp = pWl + (size_t)l * 65536 + wn * 16384 + lane * 8;

        // ---- MFMA: A from LDS, B ring depth-1 ----
        f32x4 acc[2][4];
#pragma unroll
        for (int m = 0; m < 2; ++m)
#pragma unroll
            for (int n = 0; n < 4; ++n) acc[m][n] = (f32x4){0.f, 0.f, 0.f, 0.f};

#pragma unroll
        for (int ks = 0; ks < 8; ++ks) {
            int cur = ks & 1, nxt = cur ^ 1;
            if (ks < 7) {
#pragma unroll
                for (int n = 0; n < 4; ++n) {
                    bhd[nxt][n].u = *(const u16x8*)&bhp[n * 4096 + (ks + 1) * 512];
                    bld[nxt][n].u = *(const u16x8*)&blp[n * 4096 + (ks + 1) * 512];
                }
            }
            V8 ah[2], al[2];
#pragma unroll
            for (int m = 0; m < 2; ++m) {
                int row = m * 16 + fr;
                int aby = row * 512 + (((ks * 4 + fq) ^ (row & 7)) << 4);
                ah[m].u = *(const u16x8*)(smem + aby);
                al[m].u = *(const u16x8*)(smem + AL_OFF + aby);
            }
#pragma unroll
            for (int m = 0; m < 2; ++m)
#pragma unroll
                for (int n = 0; n < 4; ++n) {
                    acc[m][n] = __builtin_amdgcn_mfma_f32_16x16x32_bf16(ah[m].b, bhd[cur][n].b, acc[m][n], 0, 0, 0);
                    acc[m][n] = __builtin_amdgcn_mfma_f32_16x16x32_bf16(ah[m].b, bld[cur][n].b, acc[m][n], 0, 0, 0);
                    acc[m][n] = __builtin_amdgcn_mfma_f32_16x16x32_bf16(al[m].b, bhd[cur][n].b, acc[m][n], 0, 0, 0);
                }
        }

        // ---- p1: y = h + out2 + pb; row sums; cross-wave reduce ----
        float4 pbv = *(const float4*)&pb_all[l * DM + col0];
        float4 lgv = *(const float4*)&lng_all[l * DM + col0];
        float4 lbv = *(const float4*)&lnb_all[l * DM + col0];
        float s[2][4], ss[2][4];
#pragma unroll
        for (int m = 0; m < 2; ++m)
#pragma unroll
            for (int r = 0; r < 4; ++r) {
                float y0 = hreg[m][0][r] + acc[m][0][r] + pbv.x;
                float y1 = hreg[m][1][r] + acc[m][1][r] + pbv.y;
                float y2 = hreg[m][2][r] + acc[m][2][r] + pbv.z;
                float y3 = hreg[m][3][r] + acc[m][3][r] + pbv.w;
                acc[m][0][r] = y0; acc[m][1][r] = y1;
                acc[m][2][r] = y2; acc[m][3][r] = y3;
                s[m][r]  = y0 + y1 + y2 + y3;
                ss[m][r] = y0 * y0 + y1 * y1 + y2 * y2 + y3 * y3;
            }
#pragma unroll
        for (int m = 0; m < 2; ++m)
#pragma unroll
            for (int r = 0; r < 4; ++r)
#pragma unroll
                for (int msk = 1; msk < 16; msk <<= 1) {
                    s[m][r]  += __shfl_xor(s[m][r],  msk);
                    ss[m][r] += __shfl_xor(ss[m][r], msk);
                }
        if (fr == 0) {
#pragma unroll
            for (int m = 0; m < 2; ++m)
#pragma unroll
                for (int r = 0; r < 4; ++r) {
                    int row = m * 16 + fq * 4 + r;
                    *(float*)(smem + RED_OFF + (row * 10 + wn * 2)     * 4) = s[m][r];
                    *(float*)(smem + RED_OFF + (row * 10 + wn * 2 + 1) * 4) = ss[m][r];
                }
        }
        __syncthreads();   // bar B: red ready; all A(l) reads done

        // ---- p2: LN -> o; hreg=o; write A(l+1); pooled; P_next ----
        float mean[2][4], rstd[2][4];
#pragma unroll
        for (int m = 0; m < 2; ++m)
#pragma unroll
            for (int r = 0; r < 4; ++r) {
                int row = m * 16 + fq * 4 + r;
                float st = 0.f, sst = 0.f;
#pragma unroll
                for (int w = 0; w < 4; ++w) {
                    st  += *(const float*)(smem + RED_OFF + (row * 10 + w * 2)     * 4);
                    sst += *(const float*)(smem + RED_OFF + (row * 10 + w * 2 + 1) * 4);
                }
                float mu = st * (1.f / 256.f);
                float var = sst * (1.f / 256.f) - mu * mu;
                mean[m][r] = mu;
                rstd[m][r] = rsqrtf(var + LN_EPS);
            }
        int slot = (l == 1) ? 0 : (l == 3) ? 1 : (l == 5) ? 2 : (l == 7) ? 3 : -1;
        bool last = (l == NLAYER - 1);
        bool prod = !last && isProd;
        float4 Dnv, lanv;
        if (!last) Dnv = *(const float4*)&Dp_all[(l + 1) * DM + col0];
        if (prod)  lanv = *(const float4*)&logA_all[(l + 1) * DM + col0];
        float cs[4] = {0.f, 0.f, 0.f, 0.f};
        float pc[4] = {0.f, 0.f, 0.f, 0.f};
#pragma unroll
        for (int m = 0; m < 2; ++m)
#pragma unroll
            for (int r = 0; r < 4; ++r) {
                int row  = m * 16 + fq * 4 + r;
                int trow = blk * BM + row;
                float o0 = (acc[m][0][r] - mean[m][r]) * rstd[m][r] * lgv.x + lbv.x;
                float o1 = (acc[m][1][r] - mean[m][r]) * rstd[m][r] * lgv.y + lbv.y;
                float o2 = (acc[m][2][r] - mean[m][r]) * rstd[m][r] * lgv.z + lbv.z;
                float o3 = (acc[m][3][r] - mean[m][r]) * rstd[m][r] * lgv.w + lbv.w;
                hreg[m][0][r] = o0; hreg[m][1][r] = o1;
                hreg[m][2][r] = o2; hreg[m][3][r] = o3;
                if (slot >= 0) { cs[0] += o0; cs[1] += o1; cs[2] += o2; cs[3] += o3; }
                if (prod && trow <= EMAX) {
                    float tf = (float)trow;
                    pc[0] += o0 * __expf(tf * lanv.x);
                    pc[1] += o1 * __expf(tf * lanv.y);
                    pc[2] += o2 * __expf(tf * lanv.z);
                    pc[3] += o3 * __expf(tf * lanv.w);
                }
                if (!last) {
                    u16 sh[4], sl[4];
                    split2(gelu_fast(Dnv.x * o0), sh[0], sl[0]);
                    split2(gelu_fast(Dnv.y * o1), sh[1], sl[1]);
                    split2(gelu_fast(Dnv.z * o2), sh[2], sl[2]);
                    split2(gelu_fast(Dnv.w * o3), sh[3], sl[3]);
                    u16x4 vh = {sh[0], sh[1], sh[2], sh[3]};
                    u16x4 vl = {sl[0], sl[1], sl[2], sl[3]};
                    int aby = a_addr(row, wn, fr);
                    *(u16x4*)(smem + aby) = vh;
                    *(u16x4*)(smem + AL_OFF + aby) = vl;
                }
            }
        if (slot >= 0) {
#pragma unroll
            for (int n = 0; n < 4; ++n) {
                cs[n] += __shfl_xor(cs[n], 16);
                cs[n] += __shfl_xor(cs[n], 32);
            }
            if (lane < 16) {
#pragma unroll
                for (int n = 0; n < 4; ++n)
                    atomicAdd(&pooled[slot * (BATCH * DM) + b * DM + wn * 64 + lane * 4 + n], cs[n]);
            }
        }
        if (prod) {
#pragma unroll
            for (int n = 0; n < 4; ++n) {
                pc[n] += __shfl_xor(pc[n], 16);
                pc[n] += __shfl_xor(pc[n], 32);
            }
            if (lane < 16) {
#pragma unroll
                for (int n = 0; n < 4; ++n)
                    atomicAdd(&P_all[(size_t)(l + 1) * BATCH * DM + b * DM + wn * 64 + lane * 4 + n], pc[n]);
            }
        }

        if (!last) {
            // preload next layer's B slot 0
            const u16* bhpN = pWh + (size_t)(l + 1) * 65536 + wn * 16384 + lane * 8;
            const u16* blpN = pWl + (size_t)(l + 1) * 65536 + wn * 16384 + lane * 8;
#pragma unroll
            for (int n = 0; n < 4; ++n) {
                bhd[0][n].u = *(const u16x8*)&bhpN[n * 4096];
                bld[0][n].u = *(const u16x8*)&blpN[n * 4096];
            }
        }
        __syncthreads();   // bar C: A(l+1) staged; P atomics drained

        if (!last) {
            if (prod && tid == 0)
                __hip_atomic_fetch_add(&flags[(l + 1) * BATCH + b], 1,
                                       __ATOMIC_RELEASE, __HIP_MEMORY_SCOPE_AGENT);
            if (isTail) {
                // wait for P[l+1]; fix tail rows' A fragments in place
                if (tid == 0) {
                    while (__hip_atomic_load(&flags[(l + 1) * BATCH + b], __ATOMIC_ACQUIRE,
                                             __HIP_MEMORY_SCOPE_AGENT) < NPROD)
                        __builtin_amdgcn_s_sleep(2);
                }
                __syncthreads();
                float4 lanx = *(const float4*)&logA_all[(l + 1) * DM + col0];
                float4 cbnx = *(const float4*)&CB_all[(l + 1) * DM + col0];
                float Pn[4];
#pragma unroll
                for (int n = 0; n < 4; ++n)
                    Pn[n] = __hip_atomic_load(
                        &P_all[(size_t)(l + 1) * BATCH * DM + b * DM + col0 + n],
                        __ATOMIC_RELAXED, __HIP_MEMORY_SCOPE_AGENT);
                float lan[4] = {lanx.x, lanx.y, lanx.z, lanx.w};
                float cbn[4] = {cbnx.x, cbnx.y, cbnx.z, cbnx.w};
                float Dn[4]  = {Dnv.x, Dnv.y, Dnv.z, Dnv.w};
#pragma unroll
                for (int m = 0; m < 2; ++m)
#pragma unroll
                    for (int r = 0; r < 4; ++r) {
                        int row = m * 16 + fq * 4 + r;
                        int u = (LSEQ - 1) - ((brow + row) & (LSEQ - 1));
                        if (u <= EMAX) {
                            float uf = (float)u;
                            u16 sh[4], sl[4];
#pragma unroll
                            for (int n = 0; n < 4; ++n) {
                                float v = Dn[n] * hreg[m][n][r] +
                                          cbn[n] * __expf(uf * lan[n]) * Pn[n];
                                split2(gelu_fast(v), sh[n], sl[n]);
                            }
                            u16x4 vh = {sh[0], sh[1], sh[2], sh[3]};
                            u16x4 vl = {sl[0], sl[1], sl[2], sl[3]};
                            int aby = a_addr(row, wn, fr);
                            *(u16x4*)(smem + aby) = vh;
                            *(u16x4*)(smem + AL_OFF + aby) = vl;
                        }
                    }
                __syncthreads();
            }
        }
    }
}

// ---------------- head ----------------
__global__ void k_head(const float* __restrict__ pooled, const float* __restrict__ hW,
                       const float* __restrict__ hb, float* __restrict__ out) {
    int tid = threadIdx.x;
    if (tid >= 96) return;
    int e = tid / 24;
    int r = tid % 24;
    int b = r / 3;
    int n = r % 3;
    const float* pv = &pooled[e * (BATCH * DM) + b * DM];
    const float* wv = &hW[(e * 3 + n) * DM];
    float acc = 0.f;
    for (int c = 0; c < DM; ++c) acc += pv[c] * wv[c];
    out[e * 24 + b * 3 + n] = acc * (1.f / (float)LSEQ) + hb[e * 3 + n];
}

extern "C" void kernel_launch(void* const* d_in, const int* in_sizes, int n_in,
                              void* d_out, int out_size, void* d_ws, size_t ws_size,
                              hipStream_t stream) {
    const float* x   = (const float*)d_in[0];
    const float* inW = (const float*)d_in[1];
    const float* inb = (const float*)d_in[2];
    const float* Ap  = (const float*)d_in[3];
    const float* Bp  = (const float*)d_in[4];
    const float* Cp  = (const float*)d_in[5];
    const float* Dp  = (const float*)d_in[6];
    const float* pW  = (const float*)d_in[7];
    const float* pb  = (const float*)d_in[8];
    const float* lng = (const float*)d_in[9];
    const float* lnb = (const float*)d_in[10];
    const float* hW  = (const float*)d_in[11];
    const float* hb  = (const float*)d_in[12];
    float* out = (float*)d_out;

    float* ws = (float*)d_ws;
    float* P_all    = ws;                            // 16384
    float* logA_all = P_all + NLAYER * BATCH * DM;   // 2048
    float* CB_all   = logA_all + NLAYER * DM;        // 2048
    float* pooled   = CB_all + NLAYER * DM;          // 8192
    u16* pWh        = (u16*)(pooled + 4 * BATCH * DM);   // 524288 u16
    u16* pWl        = pWh + NLAYER * DM * DM;            // 524288 u16
    int* flags      = (int*)(pWl + NLAYER * DM * DM);    // 64 ints

    k_prep<<<264, 256, 0, stream>>>(pW, pWh, pWl, x, inW, inb, Ap, Bp, Cp,
                                    P_all, logA_all, CB_all, pooled, flags);
    k_fused<<<BATCH * BLKS, 256, 0, stream>>>(
        x, inW, inb, pWh, pWl, Dp, pb, lng, lnb,
        logA_all, CB_all, P_all, pooled, flags);
    k_head<<<1, 128, 0, stream>>>(pooled, hW, hb, out);
}